// Round 1
// 368.164 us; speedup vs baseline: 1.0929x; 1.0929x over previous
//
#include <hip/hip_runtime.h>

// ---------- types ----------
typedef __attribute__((ext_vector_type(8))) short short8;   // 8 bf16 (4 VGPR)
typedef __attribute__((ext_vector_type(4))) short short4v;  // 4 bf16
typedef __attribute__((ext_vector_type(4))) float float4v;  // 4 fp32

__device__ __forceinline__ float bf2f(short s) {
  union { float f; unsigned u; } cv; cv.u = ((unsigned)(unsigned short)s) << 16; return cv.f;
}
__device__ __forceinline__ short f2bf(float f) {   // RNE fp32->bf16, inputs never NaN
  union { float f; unsigned u; } cv; cv.f = f;
  unsigned u = cv.u;
  unsigned r = u + 0x7FFFu + ((u >> 16) & 1u);
  return (short)(r >> 16);
}
// exact-enough GELU: erf via Abramowitz-Stegun 7.1.26 (|eps|<=1.5e-7, far below
// bf16 quantization). ~13 VALU ops, branch-free, vs ocml erff's long branchy poly.
__device__ __forceinline__ float gelu_f(float v) {
  float ax = fabsf(v) * 0.70710678118654752440f;
  float t = __builtin_amdgcn_rcpf(__builtin_fmaf(0.3275911f, ax, 1.0f));
  float poly = __builtin_fmaf(t, 1.061405429f, -1.453152027f);
  poly = __builtin_fmaf(t, poly, 1.421413741f);
  poly = __builtin_fmaf(t, poly, -0.284496736f);
  poly = __builtin_fmaf(t, poly, 0.254829592f);
  poly *= t;
  float e = __expf(-ax * ax);
  float erfax = __builtin_fmaf(-poly, e, 1.0f);     // erf(|x|)
  float erfx = (v < 0.0f) ? -erfax : erfax;
  return 0.5f * v * (1.0f + erfx);
}
// async global->LDS, 16 B per lane; LDS dest = wave-uniform base + lane*16
__device__ __forceinline__ void glds16(const short* g, short* l) {
  __builtin_amdgcn_global_load_lds(
      (const __attribute__((address_space(1))) void*)g,
      (__attribute__((address_space(3))) void*)l, 16, 0, 0);
}

// ---------- fused encoder, 4-way nc-split  (+ hidden A-power squaring chain) ----------
// block (x<512, y): accumulates GEMM2 over 2 mid-chunks, writes fp32 partial.
// block (x==512, y==0): the 11-step A^(2^k) squaring chain (global-only, register
//   lean; each step writes FRESH step-indexed addresses -> same-kernel RAW through
//   L2 is safe after __syncthreads() which drains vmcnt). Hidden under the encoder.
// LDS XOR-swizzle: tile[row][seg^(row&7)] (seg = 16B unit) -> frag reads <=2-way.
__global__ __launch_bounds__(256) void enc_fused(
    const short* __restrict__ xB, const short* __restrict__ w1T,
    const short* __restrict__ w2T, const float* __restrict__ b1,
    float* __restrict__ encP, const int* __restrict__ seq_lens,
    short* Spow, short* SpowT)
{
  int tid = threadIdx.x, lane = tid & 63, wave = tid >> 6;
  int l15 = lane & 15, quad = lane >> 4;

  if (blockIdx.x == 512) {                    // ---- fused pow_chain (1 block) ----
    if (blockIdx.y != 0) return;
    for (int step = 1; step <= 11; ++step) {
      const short* pX  = Spow  + (size_t)(step - 1) * 16384;
      const short* pXT = SpowT + (size_t)(step - 1) * 16384;
      short* gX  = Spow  + (size_t)step * 16384;
      short* gXT = SpowT + (size_t)step * 16384;
      float4v acc[2][8];
#pragma unroll
      for (int mt = 0; mt < 2; mt++)
#pragma unroll
        for (int nt = 0; nt < 8; nt++) acc[mt][nt] = 0;
#pragma unroll 1
      for (int ks = 0; ks < 4; ++ks) {
        short8 af0 = *(const short8*)&pX[(wave * 32 + l15) * 128 + ks * 32 + quad * 8];
        short8 af1 = *(const short8*)&pX[(wave * 32 + 16 + l15) * 128 + ks * 32 + quad * 8];
#pragma unroll
        for (int nt = 0; nt < 8; ++nt) {
          short8 bf = *(const short8*)&pXT[(nt * 16 + l15) * 128 + ks * 32 + quad * 8];
          acc[0][nt] = __builtin_amdgcn_mfma_f32_16x16x32_bf16(af0, bf, acc[0][nt], 0, 0, 0);
          acc[1][nt] = __builtin_amdgcn_mfma_f32_16x16x32_bf16(af1, bf, acc[1][nt], 0, 0, 0);
        }
      }
#pragma unroll
      for (int mt = 0; mt < 2; ++mt)
#pragma unroll
        for (int nt = 0; nt < 8; ++nt) {
          int mb = wave * 32 + mt * 16 + quad * 4;
          int n = nt * 16 + l15;
          short4v o;
#pragma unroll
          for (int reg = 0; reg < 4; ++reg) {
            short v = f2bf(acc[mt][nt][reg]);
            gX[(mb + reg) * 128 + n] = v;
            o[reg] = v;
          }
          *(short4v*)&gXT[(size_t)n * 128 + mb] = o;
        }
      __syncthreads();                        // drain stores; next step reads them
    }
    return;
  }

  int m0 = blockIdx.x * 64;
  { int b = m0 >> 12, t = m0 & 4095; if (t >= seq_lens[b]) return; }
  int nc0 = blockIdx.y * 2;

  __shared__ __align__(16) short As[64 * 64];     // x tile, 8 KB
  __shared__ __align__(16) short Ws[128 * 64];    // w1/w2 chunk, 16 KB
  __shared__ __align__(16) short midb[64 * 128];  // GELU-mid chunk, 16 KB

  int lr = lane >> 3, lseg = lane & 7;

  float4v accO[4][2];
#pragma unroll
  for (int i = 0; i < 4; i++)
#pragma unroll
    for (int j = 0; j < 2; j++) accO[i][j] = 0;

  for (int nci = 0; nci < 2; ++nci) {
    int nc = nc0 + nci;
    float4v accM[4][2];
#pragma unroll
    for (int i = 0; i < 4; i++)
#pragma unroll
      for (int j = 0; j < 2; j++) accM[i][j] = 0;

    // ---- GEMM1 chunk: mid[64][128] = x[64][384] @ w1T[nc*128..+128][384]^T ----
    for (int ks = 0; ks < 6; ++ks) {
      int kk = ks * 64;
#pragma unroll
      for (int i = 0; i < 2; i++) {                 // x: 64 rows
        int rowg = wave * 16 + i * 8;
        glds16(xB + (size_t)(m0 + rowg + lr) * 384 + kk + (lseg ^ lr) * 8, &As[rowg * 64]);
      }
#pragma unroll
      for (int i = 0; i < 4; i++) {                 // w1 chunk: 128 rows
        int rowg = wave * 32 + i * 8;
        glds16(w1T + (size_t)(nc * 128 + rowg + lr) * 384 + kk + (lseg ^ lr) * 8, &Ws[rowg * 64]);
      }
      __syncthreads();
#pragma unroll
      for (int kh = 0; kh < 2; kh++) {
        int s = kh * 4 + quad;
        short8 af[4], bfr[2];
#pragma unroll
        for (int im = 0; im < 4; im++) {
          int r = im * 16 + l15;
          af[im] = *(short8*)&As[r * 64 + ((s ^ (r & 7)) * 8)];
        }
#pragma unroll
        for (int in = 0; in < 2; in++) {
          int r = wave * 32 + in * 16 + l15;
          bfr[in] = *(short8*)&Ws[r * 64 + ((s ^ (r & 7)) * 8)];
        }
#pragma unroll
        for (int im = 0; im < 4; im++)
#pragma unroll
          for (int in = 0; in < 2; in++)
            accM[im][in] = __builtin_amdgcn_mfma_f32_16x16x32_bf16(af[im], bfr[in], accM[im][in], 0, 0, 0);
      }
      __syncthreads();
    }
    // ---- GELU epilogue -> midb (A-operand layout, swizzled) ----
#pragma unroll
    for (int in = 0; in < 2; in++) {
      int k = wave * 32 + in * 16 + l15;            // mid column
      float bias = b1[nc * 128 + k];
      int s = k >> 3, kb = k & 7;
#pragma unroll
      for (int im = 0; im < 4; im++)
#pragma unroll
        for (int reg = 0; reg < 4; reg++) {
          int m = im * 16 + quad * 4 + reg;
          float v = gelu_f(accM[im][in][reg] + bias);
          int sw = (s & 8) | ((s & 7) ^ (m & 7));
          midb[m * 128 + sw * 8 + kb] = f2bf(v);
        }
    }
    __syncthreads();
    // ---- GEMM2 chunk: accO += mid[64][128] @ w2T[0..128][nc*128..+128]^T ----
#pragma unroll
    for (int ks2 = 0; ks2 < 2; ++ks2) {
      int kk = nc * 128 + ks2 * 64;
#pragma unroll
      for (int i = 0; i < 4; i++) {                 // w2 chunk: 128 rows (out cols)
        int rowg = wave * 32 + i * 8;
        glds16(w2T + (size_t)(rowg + lr) * 1024 + kk + (lseg ^ lr) * 8, &Ws[rowg * 64]);
      }
      __syncthreads();
#pragma unroll
      for (int kh = 0; kh < 2; kh++) {
        short8 af[4], bfr[2];
#pragma unroll
        for (int im = 0; im < 4; im++) {
          int m = im * 16 + l15;
          int kb = ks2 * 64 + kh * 32 + quad * 8;
          int s = kb >> 3;
          int sw = (s & 8) | ((s & 7) ^ (m & 7));
          af[im] = *(short8*)&midb[m * 128 + sw * 8];
        }
#pragma unroll
        for (int in = 0; in < 2; in++) {
          int r = wave * 32 + in * 16 + l15;
          int s = kh * 4 + quad;
          bfr[in] = *(short8*)&Ws[r * 64 + ((s ^ (r & 7)) * 8)];
        }
#pragma unroll
        for (int im = 0; im < 4; im++)
#pragma unroll
          for (int in = 0; in < 2; in++)
            accO[im][in] = __builtin_amdgcn_mfma_f32_16x16x32_bf16(af[im], bfr[in], accO[im][in], 0, 0, 0);
      }
      __syncthreads();
    }
  }
  // ---- write fp32 partial slice (no bias; reduce adds it) ----
  float* outp = encP + ((size_t)blockIdx.y << 22);   // 32768*128 = 1<<22
#pragma unroll
  for (int im = 0; im < 4; im++)
#pragma unroll
    for (int in = 0; in < 2; in++) {
      int n = wave * 32 + in * 16 + l15;
#pragma unroll
      for (int reg = 0; reg < 4; reg++) {
        int m = m0 + im * 16 + quad * 4 + reg;
        outp[(size_t)m * 128 + n] = accO[im][in][reg];
      }
    }
}

// ---------- enc_reduce (+ hidden pow_fill blocks 512..637) ----------
// blocks <512: seqs = bf16( sum_y encP[y] + b2 ), masked tiles skipped.
// blocks >=512: one A-power table slot via seed-product chain; cur in LDS,
//   B-fragments streamed from global SpowT (L2-hot, written by prev kernel).
__global__ __launch_bounds__(256) void enc_reduce(
    const float* __restrict__ encP, const float* __restrict__ b2,
    short* __restrict__ seqs, const int* __restrict__ seq_lens,
    const short* __restrict__ Spow, const short* __restrict__ SpowT,
    short* __restrict__ P1, short* __restrict__ P1t, short* __restrict__ P2t)
{
  __shared__ short cur[16384];                 // 32 KB (pow_fill path only)
  if (blockIdx.x >= 512) {                     // ---- fused pow_fill ----
    int bid = blockIdx.x - 512;
    int table1 = bid < 63 ? 1 : 0;
    int e = table1 ? bid + 1 : bid - 62;
    int t = threadIdx.x, lane = t & 63, wave = t >> 6;
    int l15 = lane & 15, quad = lane >> 4;
    int bits = e;
    int k0 = __ffs(bits) - 1; bits &= bits - 1;
    int s0 = table1 ? k0 : (k0 == 0 ? 6 : 6 + k0);
    for (int i = t * 8; i < 16384; i += 2048)
      *(short8*)&cur[i] = *(const short8*)&Spow[(size_t)s0 * 16384 + i];
    while (bits) {
      int k = __ffs(bits) - 1; bits &= bits - 1;
      int si = table1 ? k : (k == 0 ? 6 : 6 + k);
      const short* Bt = SpowT + (size_t)si * 16384;
      __syncthreads();                         // cur staged / prev write visible
      float4v acc[2][8];
#pragma unroll
      for (int mt = 0; mt < 2; mt++)
#pragma unroll
        for (int nt = 0; nt < 8; nt++) acc[mt][nt] = 0;
#pragma unroll 1
      for (int ks = 0; ks < 4; ++ks) {
        short8 af0 = *(short8*)&cur[(wave * 32 + l15) * 128 + ks * 32 + quad * 8];
        short8 af1 = *(short8*)&cur[(wave * 32 + 16 + l15) * 128 + ks * 32 + quad * 8];
#pragma unroll
        for (int nt = 0; nt < 8; ++nt) {
          short8 bf = *(const short8*)&Bt[(nt * 16 + l15) * 128 + ks * 32 + quad * 8];
          acc[0][nt] = __builtin_amdgcn_mfma_f32_16x16x32_bf16(af0, bf, acc[0][nt], 0, 0, 0);
          acc[1][nt] = __builtin_amdgcn_mfma_f32_16x16x32_bf16(af1, bf, acc[1][nt], 0, 0, 0);
        }
      }
      __syncthreads();                         // frag reads done before overwrite
#pragma unroll
      for (int mt = 0; mt < 2; ++mt)
#pragma unroll
        for (int nt = 0; nt < 8; ++nt)
#pragma unroll
          for (int reg = 0; reg < 4; ++reg) {
            int m = wave * 32 + mt * 16 + quad * 4 + reg;
            int n = nt * 16 + l15;
            cur[m * 128 + n] = f2bf(acc[mt][nt][reg]);
          }
    }
    __syncthreads();
    int slot = 63 - e;
    for (int idx = t; idx < 16384; idx += 256) {
      int i = idx >> 7, j = idx & 127;
      short v = cur[idx];
      if (table1) {
        P1[i * 8192 + slot * 128 + j] = v;
        P1t[(slot * 128 + j) * 128 + i] = v;
      } else {
        P2t[(slot * 128 + j) * 128 + i] = v;
      }
    }
    return;
  }

  int m0 = blockIdx.x * 64;
  { int b = m0 >> 12, t = m0 & 4095; if (t >= seq_lens[b]) return; }
  int t = threadIdx.x;
#pragma unroll
  for (int i = 0; i < 8; i++) {
    int f4 = t + i * 256;                   // [0,2048) float4 units in tile
    int m = m0 + (f4 >> 5);
    int cg = f4 & 31;                       // column group (4 floats)
    size_t off = (size_t)m * 128 + cg * 4;
    float4v v = *(const float4v*)&encP[off];
#pragma unroll
    for (int y = 1; y < 4; y++) {
      float4v w = *(const float4v*)&encP[((size_t)y << 22) + off];
#pragma unroll
      for (int q = 0; q < 4; q++) v[q] += w[q];
    }
    float4v bb = *(const float4v*)&b2[cg * 4];
    short4v o;
#pragma unroll
    for (int q = 0; q < 4; q++) o[q] = f2bf(v[q] + bb[q]);
    *(short4v*)&seqs[off] = o;
  }
}

// ---------- MFMA GEMM (V-GEMM): Vz[z][m][n] = sum_k A[m][k]*BT[n][k] over k-chunk z ----------
__global__ __launch_bounds__(256) void gemm_bt(
    const short* __restrict__ A_, const short* __restrict__ BT,
    float* __restrict__ out, int lda, int ldb, int ldc,
    int kSteps, int kChunk)
{
  int m0 = blockIdx.y * 128;
  int n0 = blockIdx.x * 128;
  int kBase = blockIdx.z * kChunk;

  __shared__ __align__(16) short As[128 * 64];
  __shared__ __align__(16) short Bs[128 * 64];

  int tid = threadIdx.x;
  int lane = tid & 63, wave = tid >> 6;
  int l15 = lane & 15, quad = lane >> 4;
  int wm = wave & 1, wn = wave >> 1;
  int lr = lane >> 3, lseg = lane & 7;

  float4v acc[4][4];
#pragma unroll
  for (int i = 0; i < 4; i++)
#pragma unroll
    for (int j = 0; j < 4; j++) acc[i][j] = 0;

  for (int ks = 0; ks < kSteps; ++ks) {
    int kk = kBase + ks * 64;
#pragma unroll
    for (int i = 0; i < 4; i++) {
      int rowg = wave * 32 + i * 8;
      glds16(A_ + (size_t)(m0 + rowg + lr) * lda + kk + (lseg ^ lr) * 8, &As[rowg * 64]);
      glds16(BT + (size_t)(n0 + rowg + lr) * ldb + kk + (lseg ^ lr) * 8, &Bs[rowg * 64]);
    }
    __syncthreads();
#pragma unroll
    for (int kh = 0; kh < 2; kh++) {
      int s = kh * 4 + quad;
      short8 af[4], bfr[4];
#pragma unroll
      for (int im = 0; im < 4; im++) {
        int r = wm * 64 + im * 16 + l15;
        af[im] = *(short8*)&As[r * 64 + ((s ^ (r & 7)) * 8)];
      }
#pragma unroll
      for (int in = 0; in < 4; in++) {
        int r = wn * 64 + in * 16 + l15;
        bfr[in] = *(short8*)&Bs[r * 64 + ((s ^ (r & 7)) * 8)];
      }
#pragma unroll
      for (int im = 0; im < 4; im++)
#pragma unroll
        for (int in = 0; in < 4; in++)
          acc[im][in] = __builtin_amdgcn_mfma_f32_16x16x32_bf16(af[im], bfr[in], acc[im][in], 0, 0, 0);
    }
    __syncthreads();
  }
  float* outz = out + (size_t)blockIdx.z * 65536;
#pragma unroll
  for (int im = 0; im < 4; im++)
#pragma unroll
    for (int in = 0; in < 4; in++) {
      int n = n0 + wn * 64 + in * 16 + l15;
#pragma unroll
      for (int reg = 0; reg < 4; reg++) {
        int m = m0 + wm * 64 + im * 16 + quad * 4 + reg;
        outz[(size_t)m * ldc + n] = acc[im][in][reg];
      }
    }
}

// ---------- prep: x->bf16 (mask-skipped), weight conversions, identity/A seeds ----------
__global__ void prep_wide(const float* __restrict__ x, const float* __restrict__ w1,
                          const float* __restrict__ w2,
                          const float* __restrict__ proj_w, const float* __restrict__ ffn_w1,
                          const float* __restrict__ ffn_w2, const float* __restrict__ out_w,
                          const float* __restrict__ A, const int* __restrict__ seq_lens,
                          short* __restrict__ xB,
                          short* __restrict__ w1T, short* __restrict__ w2T,
                          short* __restrict__ projB, short* __restrict__ ffn1B,
                          short* __restrict__ ffn2B, short* __restrict__ outB,
                          short* __restrict__ P1, short* __restrict__ P1t,
                          short* __restrict__ P2t,
                          short* __restrict__ Spow, short* __restrict__ SpowT)
{
  int idx = blockIdx.x * 256 + threadIdx.x;
  if (idx < 3145728) {                       // x -> bf16 (float4 units), skip masked rows
    int row = idx / 96;                      // 384 floats = 96 float4 per row
    int t = row & 4095, b = row >> 12;
    if (t >= seq_lens[b]) return;            // xB stays poison there (never used)
    float4v v = ((const float4v*)x)[idx];
    short4v o;
#pragma unroll
    for (int j = 0; j < 4; j++) o[j] = f2bf(v[j]);
    ((short4v*)xB)[idx] = o;
    return;
  }
  idx -= 3145728;
  if (idx < 393216) {                        // w1T[n][k] = w1[k][n]
    int n = idx / 384, k = idx % 384;
    w1T[idx] = f2bf(w1[k * 1024 + n]);
    return;
  }
  idx -= 393216;
  if (idx < 131072) {                        // w2T[n][k] = w2[k][n]
    int n = idx / 1024, k = idx % 1024;
    w2T[idx] = f2bf(w2[k * 128 + n]);
    return;
  }
  idx -= 131072;
  if (idx < 131072) { projB[idx] = f2bf(proj_w[idx]); return; }
  idx -= 131072;
  if (idx < 524288) { ffn1B[idx] = f2bf(ffn_w1[idx]); return; }
  idx -= 524288;
  if (idx < 524288) { ffn2B[idx] = f2bf(ffn_w2[idx]); return; }
  idx -= 524288;
  if (idx < 1048576) { outB[idx] = f2bf(out_w[idx]); return; }
  idx -= 1048576;
  if (idx < 16384) {                         // identity slots (e=0) + A seed
    int i = idx >> 7, j = idx & 127;
    short bidv = f2bf((i == j) ? 1.0f : 0.0f);
    P1[i * 8192 + 63 * 128 + j] = bidv;
    P1t[(63 * 128 + j) * 128 + i] = bidv;
    P2t[(63 * 128 + j) * 128 + i] = bidv;
    short ab = f2bf(A[idx]);
    Spow[idx] = ab;                          // A^1 row-major
    SpowT[(size_t)j * 128 + i] = ab;         // transposed
  }
}

// ---------- combine: build shifted inputs in LDS (z-sum of Vz / tail from seqs) + GEMM ----------
// blocks: pp in {0:hF via P2, 1:tail via P1} x 32 k-slices of 256
__global__ __launch_bounds__(256) void combine_gemm(
    const float* __restrict__ Vz, const short* __restrict__ seqs,
    const int* __restrict__ seq_lens,
    const short* __restrict__ P2t, const short* __restrict__ P1t,
    float* __restrict__ hFtail)
{
  __shared__ short X[256 * 8];   // [k_local][b] bf16
  int pp = blockIdx.x >> 5, ks = blockIdx.x & 31;
  int t = threadIdx.x;
  for (int e = t; e < 2048; e += 256) {
    int klocal = e >> 3, b = e & 7;
    int cp = ks * 2 + (klocal >> 7), i = klocal & 127;
    int L = seq_lens[b];
    if (pp == 0) {
      int F = L >> 6, sh = 64 - F;
      float v = 0.f;
      if (cp >= sh) {
        int row = (b * 64 + (cp - sh)) * 128 + i;
#pragma unroll
        for (int z = 0; z < 32; z++) v += Vz[(size_t)z * 65536 + row];
      }
      X[e] = f2bf(v);
    } else {
      int F = L >> 6, rr = L & 63, sh = 64 - rr;
      short s = 0;
      if (cp >= sh) s = seqs[((size_t)b * 4096 + F * 64 + (cp - sh)) * 128 + i];
      X[e] = s;
    }
  }
  __syncthreads();
  const short* P = pp ? P1t : P2t;
  float* outp = hFtail + pp * 1024;
  int i = t & 127, g = t >> 7;
  float acc[4] = {0, 0, 0, 0};
  for (int kl = 0; kl < 256; ++kl) {
    int k = ks * 256 + kl;
    float pv = bf2f(P[k * 128 + i]);
    short4v xv = *(const short4v*)(X + kl * 8 + g * 4);
#pragma unroll
    for (int q = 0; q < 4; q++) acc[q] += bf2f(xv[q]) * pv;
  }
#pragma unroll
  for (int q = 0; q < 4; q++) atomicAdd(&outp[(g * 4 + q) * 128 + i], acc[q]);
}

// ---------- decoder stage 1: h = A^rr hF + tail, proj matvec ----------
__global__ __launch_bounds__(256) void proj_stage(
    const float* __restrict__ hFtail, const short* __restrict__ P1t,
    const int* __restrict__ seq_lens, const short* __restrict__ projB,
    const float* __restrict__ proj_b, float* __restrict__ projected)
{
  __shared__ short hT[128 * 8];        // bf16 [k][b]
  __shared__ float red[4][64][8];
  int t = threadIdx.x;
  {
    int b = t >> 5, i4 = (t & 31) * 4;
    int rr = seq_lens[b] & 63;
    const short* M = P1t + (size_t)(63 - rr) * 128 * 128;   // (A^rr)[i][j] = M[j*128+i]
    const float* hF = hFtail + b * 128;
    float acc[4];
#pragma unroll
    for (int q = 0; q < 4; q++) acc[q] = hFtail[1024 + b * 128 + i4 + q];  // tail
    for (int j = 0; j < 128; ++j) {
      float hv = hF[j];
      short4v mv = *(const short4v*)&M[j * 128 + i4];
#pragma unroll
      for (int q = 0; q < 4; q++) acc[q] += bf2f(mv[q]) * hv;
    }
#pragma unroll
    for (int q = 0; q < 4; q++) hT[(i4 + q) * 8 + b] = f2bf(acc[q]);
  }
  __syncthreads();
  int c = t & 63, sl = t >> 6;
  int n = blockIdx.x * 64 + c;
  float acc[8] = {0, 0, 0, 0, 0, 0, 0, 0};
  for (int k = sl * 32; k < sl * 32 + 32; ++k) {
    short8 xv = *(short8*)&hT[k * 8];
    float wv = bf2f(projB[k * 1024 + n]);
#pragma unroll
    for (int b = 0; b < 8; b++) acc[b] += bf2f(xv[b]) * wv;
  }
#pragma unroll
  for (int b = 0; b < 8; b++) red[sl][c][b] = acc[b];
  __syncthreads();
  if (sl == 0) {
#pragma unroll
    for (int s = 1; s < 4; s++)
#pragma unroll
      for (int b = 0; b < 8; b++) acc[b] += red[s][c][b];
    float bn = proj_b[n];
#pragma unroll
    for (int b = 0; b < 8; b++) projected[b * 1024 + n] = acc[b] + bn;
  }
}

// ---------- decoder stage 2: LN1(projected) @ ffn_w1 -> ffn1raw ----------
__global__ __launch_bounds__(256) void ffn1_stage(
    const float* __restrict__ projected, const float* __restrict__ g1,
    const float* __restrict__ b1, const short* __restrict__ ffn1B,
    float* __restrict__ ffn1raw)
{
  __shared__ float part[8][32][2];
  __shared__ float stats[8][2];
  __shared__ short xT[256 * 8];
  __shared__ float red[4][64][8];
  int t = threadIdx.x;
  { int b = t >> 5, j0 = t & 31; float s = 0, q = 0;
    for (int k = j0 * 32; k < j0 * 32 + 32; ++k) { float v = projected[b * 1024 + k]; s += v; q += v * v; }
    part[b][j0][0] = s; part[b][j0][1] = q; }
  __syncthreads();
  if (t < 8) {
    float s = 0, q = 0;
    for (int j = 0; j < 32; j++) { s += part[t][j][0]; q += part[t][j][1]; }
    float mu = s * (1.0f / 1024.0f);
    float var = q * (1.0f / 1024.0f) - mu * mu;
    stats[t][0] = mu; stats[t][1] = rsqrtf(var + 1e-5f);
  }
  __syncthreads();
  int ky0 = blockIdx.y * 256;
  for (int idx = t; idx < 2048; idx += 256) {
    int kl = idx >> 3, b = idx & 7; int k = ky0 + kl;
    float v = (projected[b * 1024 + k] - stats[b][0]) * stats[b][1] * g1[k] + b1[k];
    xT[kl * 8 + b] = f2bf(v);
  }
  __syncthreads();
  int c = t & 63, sl = t >> 6;
  int n = blockIdx.x * 64 + c;
  float acc[8] = {0, 0, 0, 0, 0, 0, 0, 0};
  for (int kl = sl * 64; kl < sl * 64 + 64; ++kl) {
    short8 xv = *(short8*)&xT[kl * 8];
    float wv = bf2f(ffn1B[(size_t)(ky0 + kl) * 512 + n]);
#pragma unroll
    for (int b = 0; b < 8; b++) acc[b] += bf2f(xv[b]) * wv;
  }
#pragma unroll
  for (int b = 0; b < 8; b++) red[sl][c][b] = acc[b];
  __syncthreads();
  if (sl == 0) {
#pragma unroll
    for (int s = 1; s < 4; s++)
#pragma unroll
      for (int b = 0; b < 8; b++) acc[b] += red[s][c][b];
#pragma unroll
    for (int b = 0; b < 8; b++) atomicAdd(&ffn1raw[b * 512 + n], acc[b]);
  }
}

// ---------- decoder stage 3: gelu(ffn1raw + b1) @ ffn_w2 -> ffn2raw ----------
__global__ __launch_bounds__(256) void ffn2_stage(
    const float* __restrict__ ffn1raw, const float* __restrict__ fb1,
    const short* __restrict__ ffn2B, float* __restrict__ ffn2raw)
{
  __shared__ short xT[256 * 8];
  __shared__ float red[4][64][8];
  int t = threadIdx.x;
  int ky0 = blockIdx.y * 256;
  for (int idx = t; idx < 2048; idx += 256) {
    int kl = idx >> 3, b = idx & 7; int k = ky0 + kl;
    float v = gelu_f(ffn1raw[b * 512 + k] + fb1[k]);
    xT[kl * 8 + b] = f2bf(v);
  }
  __syncthreads();
  int c = t & 63, sl = t >> 6;
  int n = blockIdx.x * 64 + c;
  float acc[8] = {0, 0, 0, 0, 0, 0, 0, 0};
  for (int kl = sl * 64; kl < sl * 64 + 64; ++kl) {
    short8 xv = *(short8*)&xT[kl * 8];
    float wv = bf2f(ffn2B[(size_t)(ky0 + kl) * 1024 + n]);
#pragma unroll
    for (int b = 0; b < 8; b++) acc[b] += bf2f(xv[b]) * wv;
  }
#pragma unroll
  for (int b = 0; b < 8; b++) red[sl][c][b] = acc[b];
  __syncthreads();
  if (sl == 0) {
#pragma unroll
    for (int s = 1; s < 4; s++)
#pragma unroll
      for (int b = 0; b < 8; b++) acc[b] += red[s][c][b];
#pragma unroll
    for (int b = 0; b < 8; b++) atomicAdd(&ffn2raw[b * 1024 + n], acc[b]);
  }
}

// ---------- decoder stage 4: LN2(ffn2raw + b2 + projected) @ out_w + out_b -> d_out ----------
__global__ __launch_bounds__(256) void out_stage(
    const float* __restrict__ ffn2raw, const float* __restrict__ fb2,
    const float* __restrict__ projected, const float* __restrict__ g2,
    const float* __restrict__ b2ln, const short* __restrict__ outB,
    const float* __restrict__ out_b, float* __restrict__ d_out)
{
  __shared__ float part[8][32][2];
  __shared__ float stats[8][2];
  __shared__ short xT[512 * 8];
  __shared__ float red[4][64][8];
  int t = threadIdx.x;
  { int b = t >> 5, j0 = t & 31; float s = 0, q = 0;
    for (int k = j0 * 32; k < j0 * 32 + 32; ++k) {
      float v = ffn2raw[b * 1024 + k] + fb2[k] + projected[b * 1024 + k];
      s += v; q += v * v;
    }
    part[b][j0][0] = s; part[b][j0][1] = q; }
  __syncthreads();
  if (t < 8) {
    float s = 0, q = 0;
    for (int j = 0; j < 32; j++) { s += part[t][j][0]; q += part[t][j][1]; }
    float mu = s * (1.0f / 1024.0f);
    float var = q * (1.0f / 1024.0f) - mu * mu;
    stats[t][0] = mu; stats[t][1] = rsqrtf(var + 1e-5f);
  }
  __syncthreads();
  int ky0 = blockIdx.y * 512;
  for (int idx = t; idx < 4096; idx += 256) {
    int kl = idx >> 3, b = idx & 7; int k = ky0 + kl;
    float v = ffn2raw[b * 1024 + k] + fb2[k] + projected[b * 1024 + k];
    v = (v - stats[b][0]) * stats[b][1] * g2[k] + b2ln[k];
    xT[kl * 8 + b] = f2bf(v);
  }
  __syncthreads();
  int c = t & 63, sl = t >> 6;
  int n = blockIdx.x * 64 + c;
  float acc[8] = {0, 0, 0, 0, 0, 0, 0, 0};
  for (int kl = sl * 128; kl < sl * 128 + 128; ++kl) {
    short8 xv = *(short8*)&xT[kl * 8];
    float wv = bf2f(outB[(size_t)(ky0 + kl) * 1024 + n]);
#pragma unroll
    for (int b = 0; b < 8; b++) acc[b] += bf2f(xv[b]) * wv;
  }
#pragma unroll
  for (int b = 0; b < 8; b++) red[sl][c][b] = acc[b];
  __syncthreads();
  if (sl == 0) {
#pragma unroll
    for (int s = 1; s < 4; s++)
#pragma unroll
      for (int b = 0; b < 8; b++) acc[b] += red[s][c][b];
    float bn = (blockIdx.y == 0) ? out_b[n] : 0.0f;
#pragma unroll
    for (int b = 0; b < 8; b++) atomicAdd(&d_out[b * 1024 + n], acc[b] + bn);
  }
}

// ---------- host ----------
extern "C" void kernel_launch(void* const* d_in, const int* in_sizes, int n_in,
                              void* d_out, int out_size, void* d_ws, size_t ws_size,
                              hipStream_t stream)
{
  (void)in_sizes; (void)n_in; (void)out_size; (void)ws_size;
  const float* x      = (const float*)d_in[0];
  const int* seq_lens = (const int*)d_in[1];
  const float* A      = (const float*)d_in[2];
  const float* enc_w1 = (const float*)d_in[3];
  const float* enc_b1 = (const float*)d_in[4];
  const float* enc_w2 = (const float*)d_in[5];
  const float* enc_b2 = (const float*)d_in[6];
  const float* proj_w = (const float*)d_in[7];
  const float* proj_b = (const float*)d_in[8];
  const float* ln1_g  = (const float*)d_in[9];
  const float* ln1_b  = (const float*)d_in[10];
  const float* ffn_w1 = (const float*)d_in[11];
  const float* ffn_b1 = (const float*)d_in[12];
  const float* ffn_w2 = (const float*)d_in[13];
  const float* ffn_b2 = (const float*)d_in[14];
  const float* ln2_g  = (const float*)d_in[15];
  const float* ln2_b  = (const float*)d_in[16];
  const float* out_w  = (const float*)d_in[17];
  const float* out_b  = (const float*)d_in[18];

  char* p = (char*)d_ws;
  auto alloc = [&](size_t bytes) { char* r = p; p += (bytes + 255) & ~(size_t)255; return r; };
  short* xB    = (short*)alloc(32768ull * 384 * 2);     // 25 MB
  float* encP  = (float*)alloc(4ull * 32768 * 128 * 4); // 64 MB partials
  short* seqs  = (short*)alloc(32768ull * 128 * 2);     // 8.4 MB
  short* w1T   = (short*)alloc(1024ull * 384 * 2);
  short* w2T   = (short*)alloc(128ull * 1024 * 2);
  short* projB = (short*)alloc(128ull * 1024 * 2);
  short* ffn1B = (short*)alloc(1024ull * 512 * 2);
  short* ffn2B = (short*)alloc(512ull * 1024 * 2);
  short* outB  = (short*)alloc(1024ull * 1024 * 2);
  short* Spow  = (short*)alloc(12ull * 16384 * 2);
  short* SpowT = (short*)alloc(12ull * 16384 * 2);
  short* P1    = (short*)alloc(128ull * 8192 * 2);      // [i][(63-e)*128+j] = A^e
  short* P1t   = (short*)alloc(8192ull * 128 * 2);
  short* P2t   = (short*)alloc(8192ull * 128 * 2);
  float* Vz    = (float*)alloc(32ull * 512 * 128 * 4);  // 8.4 MB per-z V partials
  // ---- zeroed zone (contiguous, all sizes 256-multiples) ----
  float* hFtail  = (float*)alloc(2ull * 8 * 128 * 4);
  float* ffn1raw = (float*)alloc(8ull * 512 * 4);
  float* ffn2raw = (float*)alloc(8ull * 1024 * 4);
  // ---- end zone ----
  float* projected = (float*)alloc(8ull * 1024 * 4);

  hipMemsetAsync(hFtail, 0, (2ull * 8 * 128 + 8ull * 512 + 8ull * 1024) * 4, stream);
  hipMemsetAsync(d_out, 0, 8192ull * 4, stream);

  prep_wide<<<23104, 256, 0, stream>>>(x, enc_w1, enc_w2, proj_w, ffn_w1, ffn_w2, out_w, A,
      seq_lens, xB, w1T, w2T, projB, ffn1B, ffn2B, outB, P1, P1t, P2t, Spow, SpowT);

  // fused encoder (+ hidden pow_chain block), then reduce (+ hidden pow_fill blocks)
  enc_fused<<<dim3(513, 4), 256, 0, stream>>>(xB, w1T, w2T, enc_b1, encP, seq_lens, Spow, SpowT);
  enc_reduce<<<638, 256, 0, stream>>>(encP, enc_b2, seqs, seq_lens, Spow, SpowT, P1, P1t, P2t);

  // recurrence: per-chunk values (32-way z partials), then shifted combine + tail
  gemm_bt<<<dim3(1, 4, 32), 256, 0, stream>>>(seqs, P1, Vz, 8192, 8192, 128, 4, 256);
  combine_gemm<<<64, 256, 0, stream>>>(Vz, seqs, seq_lens, P2t, P1t, hFtail);

  // decoder
  proj_stage<<<16, 256, 0, stream>>>(hFtail, P1t, seq_lens, projB, proj_b, projected);
  ffn1_stage<<<dim3(8, 4), 256, 0, stream>>>(projected, ln1_g, ln1_b, ffn1B, ffn1raw);
  ffn2_stage<<<dim3(16, 2), 256, 0, stream>>>(ffn1raw, ffn_b1, ffn2B, ffn2raw);
  out_stage<<<dim3(16, 2), 256, 0, stream>>>(ffn2raw, ffn_b2, projected, ln2_g, ln2_b,
      outB, out_b, (float*)d_out);
}